// Round 9
// baseline (473.131 us; speedup 1.0000x reference)
//
#include <hip/hip_runtime.h>

#define CDIV(a,b) (((a)+(b)-1)/(b))

// ---------------------------------------------------------------------------
// conv0: 3->96, 64x64 -> 32x32, fully unrolled
// ---------------------------------------------------------------------------
__global__ __launch_bounds__(256) void conv3x3_c3(const float* __restrict__ in,
    const float* __restrict__ w, const float* __restrict__ bias, float* __restrict__ out)
{
    int idx = blockIdx.x * 256 + threadIdx.x;     // 10*96*32*32 = 983040 exact
    int ox = idx & 31; int t = idx >> 5;
    int oy = t & 31;   t >>= 5;
    int co = t % 96;   int b = t / 96;
    float acc = bias[co];
    const float* wp  = w + co * 27;
    const float* ipb = in + (size_t)b * 3 * 64 * 64;
    #pragma unroll
    for (int ci = 0; ci < 3; ++ci) {
        #pragma unroll
        for (int ky = 0; ky < 3; ++ky) {
            int iy = 2 * oy + ky;
            #pragma unroll
            for (int kx = 0; kx < 3; ++kx) {
                int ix = 2 * ox + kx;
                if (iy < 64 && ix < 64)
                    acc = fmaf(wp[ci * 9 + ky * 3 + kx], ipb[(ci * 64 + iy) * 64 + ix], acc);
            }
        }
    }
    out[idx] = fmaxf(acc, 0.f);
}

// ---------------------------------------------------------------------------
// conv1: ci-split-K with LDS staging (unchanged)
// ---------------------------------------------------------------------------
template<int CIN,int COUT,int HIN,int WIN,int SPLITS,int CK,int CO_R>
__global__ __launch_bounds__(256) void conv_splitk_big(const float* __restrict__ in,
    const float* __restrict__ w, float* __restrict__ partial)
{
    constexpr int HOUT = HIN/2, WOUT = WIN/2;
    constexpr int SP = HOUT * WOUT;
    static_assert(SP == 256, "one output px per thread");
    constexpr int HP = HIN + 1, WP = WIN + 2;
    constexpr int CSL = CIN / SPLITS;
    constexpr int NCH = CSL / CK;
    static_assert(CSL % CK == 0, "CK must divide ci slice");
    constexpr int SELEM = CK * HP * WP;
    constexpr int NLD = (SELEM + 255) / 256;
    __shared__ float sb[SELEM];

    const int b = blockIdx.y, s = blockIdx.z;
    const int co_base = blockIdx.x * CO_R;
    const int oy = threadIdx.x >> 4, ox = threadIdx.x & 15;
    const int ci00 = s * CSL;
    const float* inb = in + (size_t)b * CIN * HIN * WIN;

    float rg[NLD];
    auto load_chunk = [&](int ci0) {
        #pragma unroll
        for (int j = 0; j < NLD; ++j) {
            int i = threadIdx.x + j * 256;
            float v = 0.f;
            if (i < SELEM) {
                int c = i % WP; int r = (i / WP) % HP; int cl = i / (WP * HP);
                if (r < HIN && c < WIN) v = inb[((size_t)(ci0 + cl) * HIN + r) * WIN + c];
            }
            rg[j] = v;
        }
    };
    load_chunk(ci00);

    float acc[CO_R] = {};
    for (int ch = 0; ch < NCH; ++ch) {
        #pragma unroll
        for (int j = 0; j < NLD; ++j) {
            int i = threadIdx.x + j * 256;
            if (i < SELEM) sb[i] = rg[j];
        }
        __syncthreads();
        if (ch + 1 < NCH) load_chunk(ci00 + (ch + 1) * CK);

        #pragma unroll
        for (int cl = 0; cl < CK; ++cl) {
            const float* sp = &sb[(cl * HP + 2 * oy) * WP + 2 * ox];
            float x[3][3];
            #pragma unroll
            for (int dy = 0; dy < 3; ++dy) {
                float2 f = *(const float2*)&sp[dy * WP];
                x[dy][0] = f.x; x[dy][1] = f.y; x[dy][2] = sp[dy * WP + 2];
            }
            int ci = ci00 + ch * CK + cl;
            const float* wp = w + ((size_t)co_base * CIN + ci) * 9;
            #pragma unroll
            for (int r = 0; r < CO_R; ++r) {
                const float* wr = wp + (size_t)r * CIN * 9;
                #pragma unroll
                for (int dy = 0; dy < 3; ++dy)
                    #pragma unroll
                    for (int dx = 0; dx < 3; ++dx)
                        acc[r] = fmaf(wr[dy * 3 + dx], x[dy][dx], acc[r]);
            }
        }
        __syncthreads();
    }
    #pragma unroll
    for (int r = 0; r < CO_R; ++r)
        partial[(((size_t)s * 10 + b) * COUT + co_base + r) * SP + threadIdx.x] = acc[r];
}

// ---------------------------------------------------------------------------
// conv2/conv3 split-K (unchanged)
// ---------------------------------------------------------------------------
template<int CIN,int COUT,int HIN,int WIN,int CK,int CO_R,int COS>
__global__ __launch_bounds__(256) void conv_small_splitk(const float* __restrict__ in,
    const float* __restrict__ w, float* __restrict__ partial)
{
    constexpr int HOUT = HIN/2, WOUT = WIN/2;
    constexpr int SP = HOUT * WOUT;
    static_assert(SP * COS == 256, "block covers SP x COS");
    constexpr int HP = HIN + 1, WP = WIN + 2;
    __shared__ float sb[CK * HP * WP];
    const int b = blockIdx.y;
    const int s = blockIdx.z;
    const int sp_i = threadIdx.x % SP;
    const int slot = threadIdx.x / SP;
    const int co_base = (blockIdx.x * COS + slot) * CO_R;
    const int oy = sp_i / WOUT, ox = sp_i % WOUT;
    const int ci0 = s * CK;
    const float* inb = in + (size_t)b * CIN * HIN * WIN;

    for (int i = threadIdx.x; i < CK * HP * WP; i += 256) {
        int c = i % WP; int r = (i / WP) % HP; int cl = i / (WP * HP);
        float v = 0.f;
        if (r < HIN && c < WIN) v = inb[((size_t)(ci0 + cl) * HIN + r) * WIN + c];
        sb[i] = v;
    }
    __syncthreads();

    float acc[CO_R] = {};
    #pragma unroll
    for (int cl = 0; cl < CK; ++cl) {
        const float* sp = &sb[(cl * HP + 2 * oy) * WP + 2 * ox];
        float x[3][3];
        #pragma unroll
        for (int dy = 0; dy < 3; ++dy) {
            float2 f = *(const float2*)&sp[dy * WP];
            x[dy][0] = f.x; x[dy][1] = f.y; x[dy][2] = sp[dy * WP + 2];
        }
        const float* wp = w + ((size_t)co_base * CIN + (ci0 + cl)) * 9;
        #pragma unroll
        for (int r = 0; r < CO_R; ++r) {
            const float* wr = wp + (size_t)r * CIN * 9;
            #pragma unroll
            for (int dy = 0; dy < 3; ++dy)
                #pragma unroll
                for (int dx = 0; dx < 3; ++dx)
                    acc[r] = fmaf(wr[dy * 3 + dx], x[dy][dx], acc[r]);
        }
    }
    #pragma unroll
    for (int r = 0; r < CO_R; ++r)
        partial[(((size_t)s * 10 + b) * COUT + co_base + r) * SP + sp_i] = acc[r];
}

template<int COUT,int SP,int S>
__global__ void conv_reduce_relu(const float* __restrict__ partial, const float* __restrict__ bias,
                                 float* __restrict__ out, int total)
{
    int i = blockIdx.x * 256 + threadIdx.x;
    if (i >= total) return;
    int sp = i % SP; int co = (i / SP) % COUT; int b = i / (SP * COUT);
    float acc = bias[co];
    #pragma unroll
    for (int s = 0; s < S; ++s) acc += partial[(((size_t)s * 10 + b) * COUT + co) * SP + sp];
    out[i] = fmaxf(acc, 0.f);
}

// ---------------------------------------------------------------------------
// d0/d1 split-K quad (unchanged)
// ---------------------------------------------------------------------------
template<int CIN,int COUT,int HIN,int CK,int CO_R,int QPW>
__global__ __launch_bounds__(256) void deconv_quad_splitk(const float* __restrict__ in,
    const float* __restrict__ w, float* __restrict__ partial)
{
    constexpr int CPW = 64 / QPW;
    constexpr int HP2 = HIN + 2;
    constexpr int SP = 4 * HIN * HIN;
    constexpr int WOUT = 2 * HIN;
    static_assert(QPW == HIN * HIN, "wave quads cover input plane");
    __shared__ float sb[CK * HP2 * HP2];
    const int b = blockIdx.y, s = blockIdx.z;
    const int lane = threadIdx.x & 63;
    const int wv = threadIdx.x >> 6;
    const int q = lane % QPW;
    const int co_off = lane / QPW;
    const int t = q / HIN, u = q % HIN;
    const int co_base = (blockIdx.x * 4 + wv) * CPW * CO_R + co_off * CO_R;
    const int ci0 = s * CK;
    const float* inb = in + (size_t)b * CIN * HIN * HIN;

    for (int i = threadIdx.x; i < CK * HP2 * HP2; i += 256) {
        int c = i % HP2; int r = (i / HP2) % HP2; int cl = i / (HP2 * HP2);
        int gr = r - 1, gc = c - 1;
        float v = 0.f;
        if (gr >= 0 && gr < HIN && gc >= 0 && gc < HIN)
            v = inb[((size_t)(ci0 + cl) * HIN + gr) * HIN + gc];
        sb[i] = v;
    }
    __syncthreads();

    float acc[CO_R][4] = {};
    #pragma unroll 4
    for (int cl = 0; cl < CK; ++cl) {
        const float* sp = &sb[(cl * HP2 + t) * HP2 + u];
        float x00 = sp[0],       x01 = sp[1],       x02 = sp[2];
        float x10 = sp[HP2],     x11 = sp[HP2+1],   x12 = sp[HP2+2];
        float x20 = sp[2*HP2],   x21 = sp[2*HP2+1], x22 = sp[2*HP2+2];
        const float* wp = w + ((size_t)(ci0 + cl) * COUT + co_base) * 16;
        #pragma unroll
        for (int r = 0; r < CO_R; ++r) {
            const float* W_ = wp + r * 16;
            acc[r][0] += W_[5]*x11 + W_[7]*x10 + W_[13]*x01 + W_[15]*x00;
            acc[r][1] += W_[4]*x12 + W_[6]*x11 + W_[12]*x02 + W_[14]*x01;
            acc[r][2] += W_[1]*x21 + W_[3]*x20 + W_[9]*x11  + W_[11]*x10;
            acc[r][3] += W_[0]*x22 + W_[2]*x21 + W_[8]*x12  + W_[10]*x11;
        }
    }
    #pragma unroll
    for (int r = 0; r < CO_R; ++r) {
        float* pp = partial + (((size_t)s * 10 + b) * COUT + co_base + r) * SP;
        pp[(2*t)   * WOUT + 2*u]     = acc[r][0];
        pp[(2*t)   * WOUT + 2*u + 1] = acc[r][1];
        pp[(2*t+1) * WOUT + 2*u]     = acc[r][2];
        pp[(2*t+1) * WOUT + 2*u + 1] = acc[r][3];
    }
}

// ---------------------------------------------------------------------------
// d3/d4 DIRECT v2: ALL co-groups in one block (wave = co group, all waves
// share the same spatial tile -> input fetched from HBM once, served by
// L1/L2 for the other waves). QH vertical quads per thread: QH+2 rows x 3
// cols of loads feed QH*CO_R*16 FMAs per ci. No LDS, no barriers.
// ---------------------------------------------------------------------------
template<int CIN,int COUT,int HIN,int CO_R,int NW,int QH>
__global__ __launch_bounds__(NW*64) void deconv_quad_direct2(const float* __restrict__ in,
    const float* __restrict__ w, const float* __restrict__ bias, float* __restrict__ out)
{
    constexpr int WIN = HIN, HOUT = 2 * HIN, WOUT = 2 * WIN;
    constexpr int TILES_U = WIN / 8;
    static_assert(NW * CO_R == COUT, "waves cover all cos");
    static_assert(HIN % (8 * QH) == 0, "tiles divide");

    const int lane = threadIdx.x & 63;
    const int wv   = __builtin_amdgcn_readfirstlane((int)(threadIdx.x >> 6));
    const int tt = blockIdx.x / TILES_U, tu = blockIdx.x % TILES_U;
    const int b  = blockIdx.y;
    const int co_base = wv * CO_R;
    const int t0 = tt * 8 * QH + (lane >> 3) * QH;
    const int u  = tu * 8 + (lane & 7);

    const bool mc0 = u > 0, mc2 = u < WIN - 1;
    const int um = mc0 ? u - 1 : u, up = mc2 ? u + 1 : u;

    int roff[QH + 2]; bool rv[QH + 2];
    #pragma unroll
    for (int j = 0; j < QH + 2; ++j) {
        int row = t0 - 1 + j;
        rv[j] = (row >= 0) && (row < HIN);
        int rc = row < 0 ? 0 : (row >= HIN ? HIN - 1 : row);
        roff[j] = rc * WIN;
    }

    const float* p = in + (size_t)b * CIN * HIN * WIN;
    float acc[CO_R][QH][4] = {};

    for (int ci = 0; ci < CIN; ++ci) {
        float xr[QH + 2][3];
        #pragma unroll
        for (int j = 0; j < QH + 2; ++j) {
            float a = p[roff[j] + um], bb = p[roff[j] + u], c = p[roff[j] + up];
            xr[j][0] = (rv[j] && mc0) ? a : 0.f;
            xr[j][1] = rv[j] ? bb : 0.f;
            xr[j][2] = (rv[j] && mc2) ? c : 0.f;
        }
        const float* wp = w + ((size_t)ci * COUT + co_base) * 16;   // wave-uniform
        #pragma unroll
        for (int r = 0; r < CO_R; ++r) {
            const float* W_ = wp + r * 16;
            #pragma unroll
            for (int q = 0; q < QH; ++q) {
                float x00 = xr[q][0],   x01 = xr[q][1],   x02 = xr[q][2];
                float x10 = xr[q+1][0], x11 = xr[q+1][1], x12 = xr[q+1][2];
                float x20 = xr[q+2][0], x21 = xr[q+2][1], x22 = xr[q+2][2];
                acc[r][q][0] += W_[5]*x11 + W_[7]*x10 + W_[13]*x01 + W_[15]*x00;
                acc[r][q][1] += W_[4]*x12 + W_[6]*x11 + W_[12]*x02 + W_[14]*x01;
                acc[r][q][2] += W_[1]*x21 + W_[3]*x20 + W_[9]*x11  + W_[11]*x10;
                acc[r][q][3] += W_[0]*x22 + W_[2]*x21 + W_[8]*x12  + W_[10]*x11;
            }
        }
        p += HIN * WIN;
    }

    #pragma unroll
    for (int r = 0; r < CO_R; ++r) {
        int co = co_base + r;
        float bi = bias[co];
        #pragma unroll
        for (int q = 0; q < QH; ++q) {
            float* ob = out + (((size_t)b * COUT + co) * HOUT + 2 * (t0 + q)) * WOUT + 2 * u;
            float2 v0, v1;
            v0.x = fmaxf(acc[r][q][0] + bi, 0.f);
            v0.y = fmaxf(acc[r][q][1] + bi, 0.f);
            v1.x = fmaxf(acc[r][q][2] + bi, 0.f);
            v1.y = fmaxf(acc[r][q][3] + bi, 0.f);
            *(float2*)ob = v0;
            *(float2*)&ob[WOUT] = v1;
        }
    }
}

// ---------------------------------------------------------------------------
// Split-K FC (unchanged)
// ---------------------------------------------------------------------------
template<int KC>
__global__ __launch_bounds__(256) void fc_splitk(const float* __restrict__ in,
    const float* __restrict__ W, float* __restrict__ partial, int K, int N)
{
    __shared__ float s_in[10 * KC];
    const int o = blockIdx.x * 256 + threadIdx.x;
    const int k0 = blockIdx.y * KC;
    for (int i = threadIdx.x; i < 10 * KC; i += 256) {
        int b = i / KC, k = i % KC;
        s_in[i] = in[(size_t)b * K + k0 + k];
    }
    __syncthreads();

    float acc[10];
    #pragma unroll
    for (int b = 0; b < 10; ++b) acc[b] = 0.f;
    const float* wp = W + (size_t)k0 * N + o;
    #pragma unroll 4
    for (int k = 0; k < KC; ++k) {
        float wv = wp[(size_t)k * N];
        #pragma unroll
        for (int b = 0; b < 10; ++b) acc[b] = fmaf(wv, s_in[b * KC + k], acc[b]);
    }
    float* pp = partial + ((size_t)blockIdx.y * 10) * N + o;
    #pragma unroll
    for (int b = 0; b < 10; ++b) pp[(size_t)b * N] = acc[b];
}

__global__ void fc_reduce_relu(const float* __restrict__ partial, const float* __restrict__ bias,
                               float* __restrict__ out, int N, int S)
{
    int i = blockIdx.x * 256 + threadIdx.x;
    if (i >= 10 * N) return;
    int o = i % N, b = i / N;
    float acc = bias[o];
    for (int s = 0; s < S; ++s) acc += partial[((size_t)s * 10 + b) * N + o];
    out[(size_t)b * N + o] = fmaxf(acc, 0.f);
}

// ---------------------------------------------------------------------------
// Tiled deconv (d2 only): register-prefetch dbuf staging, Q=1 path (unchanged)
// ---------------------------------------------------------------------------
template<int CIN,int COUT,int HIN,int WIN,int Q,int TW,int NW,int CO_R,int CK,bool WAVE_CO>
__global__ __launch_bounds__(NW*64) void deconv_tiled(const float* __restrict__ in,
    const float* __restrict__ w, const float* __restrict__ bias, float* __restrict__ out)
{
    constexpr int UG = WIN / Q;
    static_assert(UG * TW == 64, "lane map must cover a 64-lane wave");
    constexpr int SPAN = WAVE_CO ? TW : NW * TW;
    static_assert(HIN % SPAN == 0, "t-span must divide HIN");
    constexpr int T_TILES = HIN / SPAN;
    constexpr int RT = SPAN + 2;
    constexpr int W2 = WIN + 2;
    constexpr int WC = (Q == 1) ? (WIN + 3) : (WIN + 2);
    constexpr int NTH = NW * 64;
    constexpr int SELEM = CK * RT * W2;
    constexpr int NLD = (SELEM + NTH - 1) / NTH;
    constexpr int NCH = CIN / CK;
    static_assert(CIN % CK == 0, "CK must divide CIN");

    __shared__ float sb[CK * RT * WC];

    const int b      = blockIdx.y;
    const int t_tile = blockIdx.x % T_TILES;
    const int cg     = blockIdx.x / T_TILES;
    const int lane   = threadIdx.x & 63;
    const int wv     = __builtin_amdgcn_readfirstlane((int)(threadIdx.x >> 6));
    const int ug     = lane % UG;
    const int tl     = lane / UG;
    const int T0     = t_tile * SPAN;
    const int co_base = WAVE_CO ? (cg * (NW * CO_R) + wv * CO_R) : (cg * CO_R);
    const int trel   = WAVE_CO ? tl : (wv * TW + tl);
    const int t      = T0 + trel;
    const int ubase  = ug * Q;

    float acc[CO_R][Q][4];
    #pragma unroll
    for (int r = 0; r < CO_R; ++r)
        #pragma unroll
        for (int q = 0; q < Q; ++q)
            #pragma unroll
            for (int k = 0; k < 4; ++k) acc[r][q][k] = 0.f;

    const float* inb = in + (size_t)b * CIN * HIN * WIN;

    float rg[NLD];
    auto load_chunk = [&](int ci0) {
        #pragma unroll
        for (int j = 0; j < NLD; ++j) {
            int i = threadIdx.x + j * NTH;
            float v = 0.f;
            if (i < SELEM) {
                int c  = i % W2;
                int rr = (i / W2) % RT;
                int cl = i / (W2 * RT);
                int grow = T0 - 1 + rr;
                int gcol = c - 1;
                if (grow >= 0 && grow < HIN && gcol >= 0 && gcol < WIN)
                    v = inb[((size_t)(ci0 + cl) * HIN + grow) * WIN + gcol];
            }
            rg[j] = v;
        }
    };

    load_chunk(0);

    for (int s = 0; s < NCH; ++s) {
        #pragma unroll
        for (int j = 0; j < NLD; ++j) {
            int i = threadIdx.x + j * NTH;
            if (i < SELEM) {
                int c  = i % W2;
                int rr = (i / W2) % RT;
                int cl = i / (W2 * RT);
                sb[(cl * RT + rr) * WC + c] = rg[j];
            }
        }
        __syncthreads();
        if (s + 1 < NCH) load_chunk((s + 1) * CK);

        #pragma unroll
        for (int cl = 0; cl < CK; ++cl) {
            float wvv[CO_R][16];
            const float* wp = w + ((size_t)(s * CK + cl) * COUT + co_base) * 16;
            #pragma unroll
            for (int r = 0; r < CO_R; ++r)
                #pragma unroll
                for (int k = 0; k < 16; ++k) wvv[r][k] = wp[r * 16 + k];

            float xv[3][Q + 2];
            const float* sp = &sb[(cl * RT + trel) * WC + ubase];
            #pragma unroll
            for (int dy = 0; dy < 3; ++dy)
                #pragma unroll
                for (int c = 0; c < Q + 2; ++c) xv[dy][c] = sp[dy * WC + c];

            #pragma unroll
            for (int r = 0; r < CO_R; ++r) {
                const float* W_ = wvv[r];
                #pragma unroll
                for (int q = 0; q < Q; ++q) {
                    float x00 = xv[0][q], x01 = xv[0][q+1], x02 = xv[0][q+2];
                    float x10 = xv[1][q], x11 = xv[1][q+1], x12 = xv[1][q+2];
                    float x20 = xv[2][q], x21 = xv[2][q+1], x22 = xv[2][q+2];
                    acc[r][q][0] += W_[5]*x11 + W_[7]*x10 + W_[13]*x01 + W_[15]*x00;
                    acc[r][q][1] += W_[4]*x12 + W_[6]*x11 + W_[12]*x02 + W_[14]*x01;
                    acc[r][q][2] += W_[1]*x21 + W_[3]*x20 + W_[9]*x11  + W_[11]*x10;
                    acc[r][q][3] += W_[0]*x22 + W_[2]*x21 + W_[8]*x12  + W_[10]*x11;
                }
            }
        }
        __syncthreads();
    }

    constexpr int HOUT = 2 * HIN, WOUT = 2 * WIN;
    #pragma unroll
    for (int r = 0; r < CO_R; ++r) {
        int co = co_base + r;
        float bi = bias[co];
        float* ob = out + (((size_t)b * COUT + co) * HOUT + 2 * t) * WOUT;
        #pragma unroll
        for (int q = 0; q < Q; ++q) {
            int ox0 = 2 * (ubase + q);
            float2 v0, v1;
            v0.x = fmaxf(acc[r][q][0] + bi, 0.f);
            v0.y = fmaxf(acc[r][q][1] + bi, 0.f);
            v1.x = fmaxf(acc[r][q][2] + bi, 0.f);
            v1.y = fmaxf(acc[r][q][3] + bi, 0.f);
            *(float2*)&ob[ox0]        = v0;
            *(float2*)&ob[WOUT + ox0] = v1;
        }
    }
}

// ---------------------------------------------------------------------------
// Final fused: 1x1 convs + geometry (unchanged)
// ---------------------------------------------------------------------------
__global__ __launch_bounds__(256) void final_fused_v2(const float* __restrict__ h,
    const float* __restrict__ xyzw, const float* __restrict__ xyzb,
    const float* __restrict__ maskw, const float* __restrict__ maskb,
    const float* __restrict__ quat, float* __restrict__ out)
{
    const int V = 8, HW = 128 * 128, C = 48, Bn = 10, VHW = V * HW;
    __shared__ float4 sh[48 * 32];
    int b = blockIdx.y, tile = blockIdx.x;
    const float4* hb = (const float4*)h;
    for (int i = threadIdx.x; i < C * 32; i += 256) {
        int ci = i >> 5, p = i & 31;
        sh[i] = hb[(size_t)(b * C + ci) * (HW / 4) + tile * 32 + p];
    }
    __syncthreads();

    int pl = threadIdx.x & 31, v = threadIdx.x >> 5;
    float4 xr = {0,0,0,0}, yr = {0,0,0,0}, zr = {0,0,0,0}, mm = {0,0,0,0};
    const float* wx = xyzw + (size_t)(v * 3 + 0) * C;
    const float* wy = xyzw + (size_t)(v * 3 + 1) * C;
    const float* wz = xyzw + (size_t)(v * 3 + 2) * C;
    const float* wm = maskw + (size_t)v * C;
    for (int ci = 0; ci < C; ++ci) {
        float4 hv = sh[ci * 32 + pl];
        float a;
        a = wx[ci]; xr.x += a*hv.x; xr.y += a*hv.y; xr.z += a*hv.z; xr.w += a*hv.w;
        a = wy[ci]; yr.x += a*hv.x; yr.y += a*hv.y; yr.z += a*hv.z; yr.w += a*hv.w;
        a = wz[ci]; zr.x += a*hv.x; zr.y += a*hv.y; zr.z += a*hv.z; zr.w += a*hv.w;
        a = wm[ci]; mm.x += a*hv.x; mm.y += a*hv.y; mm.z += a*hv.z; mm.w += a*hv.w;
    }
    float bxv = xyzb[v * 3 + 0], byv = xyzb[v * 3 + 1], bzv = xyzb[v * 3 + 2], bmv = maskb[v];

    float qw = quat[v*4+0], qx = quat[v*4+1], qy = quat[v*4+2], qz = quat[v*4+3];
    float R00 = 1.f - 2.f*(qy*qy + qz*qz), R01 = 2.f*(qx*qy - qw*qz), R02 = 2.f*(qx*qz + qw*qy);
    float R10 = 2.f*(qx*qy + qw*qz), R11 = 1.f - 2.f*(qx*qx + qz*qz), R12 = 2.f*(qy*qz - qw*qx);
    float R20 = 2.f*(qx*qz - qw*qy), R21 = 2.f*(qy*qz + qw*qx), R22 = 1.f - 2.f*(qx*qx + qy*qy);

    float4 o0, o1, o2, om;
    float* X = (float*)&xr; float* Y = (float*)&yr; float* Z = (float*)&zr; float* M = (float*)&mm;
    float* O0 = (float*)&o0; float* O1 = (float*)&o1; float* O2 = (float*)&o2; float* OM = (float*)&om;
    #pragma unroll
    for (int j = 0; j < 4; ++j) {
        float camX = (X[j] + bxv) * (1.f / 64.f) - 0.5f;
        float camY = -(Y[j] + byv) * (1.f / 64.f) + 0.5f;
        float camZ = -((Z[j] + bzv) + 1.0f);
        O0[j] = R00 * camX + R10 * camY + R20 * camZ;
        O1[j] = R01 * camX + R11 * camY + R21 * camZ;
        O2[j] = R02 * camX + R12 * camY + R22 * camZ;
        OM[j] = M[j] + bmv;
    }

    size_t o = (size_t)v * HW + tile * 128 + pl * 4;
    float4* op = (float4*)out;
    op[((size_t)(b * 3 + 0) * VHW + o) >> 2] = o0;
    op[((size_t)(b * 3 + 1) * VHW + o) >> 2] = o1;
    op[((size_t)(b * 3 + 2) * VHW + o) >> 2] = o2;
    op[((size_t)Bn * 3 * VHW + (size_t)b * VHW + o) >> 2] = om;
}

// ---------------------------------------------------------------------------

extern "C" void kernel_launch(void* const* d_in, const int* in_sizes, int n_in,
                              void* d_out, int out_size, void* d_ws, size_t ws_size,
                              hipStream_t stream)
{
    const float* x    = (const float*)d_in[0];
    const float* ew0  = (const float*)d_in[1];
    const float* eb0  = (const float*)d_in[2];
    const float* ew1  = (const float*)d_in[3];
    const float* eb1  = (const float*)d_in[4];
    const float* ew2  = (const float*)d_in[5];
    const float* eb2  = (const float*)d_in[6];
    const float* ew3  = (const float*)d_in[7];
    const float* eb3  = (const float*)d_in[8];
    const float* efw  = (const float*)d_in[9];
    const float* efb  = (const float*)d_in[10];
    const float* dfw  = (const float*)d_in[11];
    const float* dfb  = (const float*)d_in[12];
    const float* dw0  = (const float*)d_in[13];
    const float* db0  = (const float*)d_in[14];
    const float* dw1  = (const float*)d_in[15];
    const float* db1  = (const float*)d_in[16];
    const float* dw2  = (const float*)d_in[17];
    const float* db2  = (const float*)d_in[18];
    const float* dw3  = (const float*)d_in[19];
    const float* db3  = (const float*)d_in[20];
    const float* dw4  = (const float*)d_in[21];
    const float* db4  = (const float*)d_in[22];
    const float* xyzw = (const float*)d_in[23];
    const float* xyzb = (const float*)d_in[24];
    const float* maskw= (const float*)d_in[25];
    const float* maskb= (const float*)d_in[26];
    const float* quat = (const float*)d_in[27];
    float* out = (float*)d_out;

    float* A   = (float*)d_ws;
    float* Bb  = A + 7864320;
    float* P1  = A;                 // fc1 partials 128*10*512 = 655,360
    float* L   = A + 1000000;       // latent 5120
    float* P2  = Bb + 1000000;      // fc2 partials 16*10*4096 = 655,360
    float* H0  = Bb;                // fc2 out 40,960
    float* PC1 = A + 2000000;       // conv1 partials 2,621,440
    float* PC2 = A + 2000000;       // conv2 partials 983,040
    float* PC3 = Bb + 500000;       // conv3 partials 491,520
    float* PD0 = A + 2000000;       // d0 partials 491,520
    float* PD1 = Bb + 1000000;      // d1 partials 1,310,720

    const int TB = 256;

    // encoder
    conv3x3_c3<<<3840, 256, 0, stream>>>(x, ew0, eb0, A);
    conv_splitk_big<96,128,32,32,8,6,16><<<dim3(8,10,8), 256, 0, stream>>>(A, ew1, PC1);
    conv_reduce_relu<128,256,8><<<CDIV(327680,TB), TB, 0, stream>>>(PC1, eb1, Bb, 327680);
    conv_small_splitk<128,192,16,16,16,3,4><<<dim3(16,10,8), 256, 0, stream>>>(Bb, ew2, PC2);
    conv_reduce_relu<192,64,8><<<CDIV(122880,TB), TB, 0, stream>>>(PC2, eb2, A, 122880);
    conv_small_splitk<192,256,8,8,16,1,16><<<dim3(16,10,12), 256, 0, stream>>>(A, ew3, PC3);
    conv_reduce_relu<256,16,12><<<CDIV(40960,TB), TB, 0, stream>>>(PC3, eb3, Bb, 40960);

    // fc
    fc_splitk<32><<<dim3(2, 128), 256, 0, stream>>>(Bb, efw, P1, 4096, 512);
    fc_reduce_relu<<<CDIV(10 * 512, TB), TB, 0, stream>>>(P1, efb, L, 512, 128);
    fc_splitk<32><<<dim3(16, 16), 256, 0, stream>>>(L, dfw, P2, 512, 4096);
    fc_reduce_relu<<<CDIV(10 * 4096, TB), TB, 0, stream>>>(P2, dfb, H0, 4096, 16);

    // decoder
    deconv_quad_splitk<256,192,4,64,1,16><<<dim3(12,10,4), 256, 0, stream>>>(H0, dw0, PD0);
    conv_reduce_relu<192,64,4><<<CDIV(122880,TB), TB, 0, stream>>>(PD0, db0, A, 122880);
    deconv_quad_splitk<192,128,8,48,2,64><<<dim3(16,10,4), 256, 0, stream>>>(A, dw1, PD1);
    conv_reduce_relu<128,256,4><<<CDIV(327680,TB), TB, 0, stream>>>(PD1, db1, Bb, 327680);

    deconv_tiled<128, 96,16,16, 1, 4, 2, 2, 8, false><<<dim3(96, 10), 128, 0, stream>>>(Bb, dw2, db2, A);
    // d3: 16 waves (all 64 cos in one block), 1 quad/thread
    deconv_quad_direct2<96, 64, 32, 4, 16, 1><<<dim3(16, 10), 1024, 0, stream>>>(A,  dw3, db3, Bb);
    // d4: 12 waves (all 48 cos in one block), 2 vertical quads/thread
    deconv_quad_direct2<64, 48, 64, 4, 12, 2><<<dim3(32, 10), 768, 0, stream>>>(Bb, dw4, db4, A);

    // fused 1x1 convs + geometry -> d_out
    final_fused_v2<<<dim3(128, 10), 256, 0, stream>>>(A, xyzw, xyzb, maskw, maskb, quat, out);
}

// Round 10
// 438.533 us; speedup vs baseline: 1.0789x; 1.0789x over previous
//
#include <hip/hip_runtime.h>

#define CDIV(a,b) (((a)+(b)-1)/(b))

// ---------------------------------------------------------------------------
// conv0: 3->96, 64x64 -> 32x32, fully unrolled
// ---------------------------------------------------------------------------
__global__ __launch_bounds__(256) void conv3x3_c3(const float* __restrict__ in,
    const float* __restrict__ w, const float* __restrict__ bias, float* __restrict__ out)
{
    int idx = blockIdx.x * 256 + threadIdx.x;     // 10*96*32*32 = 983040 exact
    int ox = idx & 31; int t = idx >> 5;
    int oy = t & 31;   t >>= 5;
    int co = t % 96;   int b = t / 96;
    float acc = bias[co];
    const float* wp  = w + co * 27;
    const float* ipb = in + (size_t)b * 3 * 64 * 64;
    #pragma unroll
    for (int ci = 0; ci < 3; ++ci) {
        #pragma unroll
        for (int ky = 0; ky < 3; ++ky) {
            int iy = 2 * oy + ky;
            #pragma unroll
            for (int kx = 0; kx < 3; ++kx) {
                int ix = 2 * ox + kx;
                if (iy < 64 && ix < 64)
                    acc = fmaf(wp[ci * 9 + ky * 3 + kx], ipb[(ci * 64 + iy) * 64 + ix], acc);
            }
        }
    }
    out[idx] = fmaxf(acc, 0.f);
}

// ---------------------------------------------------------------------------
// conv1: ci-split-K with LDS staging (unchanged)
// ---------------------------------------------------------------------------
template<int CIN,int COUT,int HIN,int WIN,int SPLITS,int CK,int CO_R>
__global__ __launch_bounds__(256) void conv_splitk_big(const float* __restrict__ in,
    const float* __restrict__ w, float* __restrict__ partial)
{
    constexpr int HOUT = HIN/2, WOUT = WIN/2;
    constexpr int SP = HOUT * WOUT;
    static_assert(SP == 256, "one output px per thread");
    constexpr int HP = HIN + 1, WP = WIN + 2;
    constexpr int CSL = CIN / SPLITS;
    constexpr int NCH = CSL / CK;
    static_assert(CSL % CK == 0, "CK must divide ci slice");
    constexpr int SELEM = CK * HP * WP;
    constexpr int NLD = (SELEM + 255) / 256;
    __shared__ float sb[SELEM];

    const int b = blockIdx.y, s = blockIdx.z;
    const int co_base = blockIdx.x * CO_R;
    const int oy = threadIdx.x >> 4, ox = threadIdx.x & 15;
    const int ci00 = s * CSL;
    const float* inb = in + (size_t)b * CIN * HIN * WIN;

    float rg[NLD];
    auto load_chunk = [&](int ci0) {
        #pragma unroll
        for (int j = 0; j < NLD; ++j) {
            int i = threadIdx.x + j * 256;
            float v = 0.f;
            if (i < SELEM) {
                int c = i % WP; int r = (i / WP) % HP; int cl = i / (WP * HP);
                if (r < HIN && c < WIN) v = inb[((size_t)(ci0 + cl) * HIN + r) * WIN + c];
            }
            rg[j] = v;
        }
    };
    load_chunk(ci00);

    float acc[CO_R] = {};
    for (int ch = 0; ch < NCH; ++ch) {
        #pragma unroll
        for (int j = 0; j < NLD; ++j) {
            int i = threadIdx.x + j * 256;
            if (i < SELEM) sb[i] = rg[j];
        }
        __syncthreads();
        if (ch + 1 < NCH) load_chunk(ci00 + (ch + 1) * CK);

        #pragma unroll
        for (int cl = 0; cl < CK; ++cl) {
            const float* sp = &sb[(cl * HP + 2 * oy) * WP + 2 * ox];
            float x[3][3];
            #pragma unroll
            for (int dy = 0; dy < 3; ++dy) {
                float2 f = *(const float2*)&sp[dy * WP];
                x[dy][0] = f.x; x[dy][1] = f.y; x[dy][2] = sp[dy * WP + 2];
            }
            int ci = ci00 + ch * CK + cl;
            const float* wp = w + ((size_t)co_base * CIN + ci) * 9;
            #pragma unroll
            for (int r = 0; r < CO_R; ++r) {
                const float* wr = wp + (size_t)r * CIN * 9;
                #pragma unroll
                for (int dy = 0; dy < 3; ++dy)
                    #pragma unroll
                    for (int dx = 0; dx < 3; ++dx)
                        acc[r] = fmaf(wr[dy * 3 + dx], x[dy][dx], acc[r]);
            }
        }
        __syncthreads();
    }
    #pragma unroll
    for (int r = 0; r < CO_R; ++r)
        partial[(((size_t)s * 10 + b) * COUT + co_base + r) * SP + threadIdx.x] = acc[r];
}

// ---------------------------------------------------------------------------
// conv2/conv3 split-K (unchanged)
// ---------------------------------------------------------------------------
template<int CIN,int COUT,int HIN,int WIN,int CK,int CO_R,int COS>
__global__ __launch_bounds__(256) void conv_small_splitk(const float* __restrict__ in,
    const float* __restrict__ w, float* __restrict__ partial)
{
    constexpr int HOUT = HIN/2, WOUT = WIN/2;
    constexpr int SP = HOUT * WOUT;
    static_assert(SP * COS == 256, "block covers SP x COS");
    constexpr int HP = HIN + 1, WP = WIN + 2;
    __shared__ float sb[CK * HP * WP];
    const int b = blockIdx.y;
    const int s = blockIdx.z;
    const int sp_i = threadIdx.x % SP;
    const int slot = threadIdx.x / SP;
    const int co_base = (blockIdx.x * COS + slot) * CO_R;
    const int oy = sp_i / WOUT, ox = sp_i % WOUT;
    const int ci0 = s * CK;
    const float* inb = in + (size_t)b * CIN * HIN * WIN;

    for (int i = threadIdx.x; i < CK * HP * WP; i += 256) {
        int c = i % WP; int r = (i / WP) % HP; int cl = i / (WP * HP);
        float v = 0.f;
        if (r < HIN && c < WIN) v = inb[((size_t)(ci0 + cl) * HIN + r) * WIN + c];
        sb[i] = v;
    }
    __syncthreads();

    float acc[CO_R] = {};
    #pragma unroll
    for (int cl = 0; cl < CK; ++cl) {
        const float* sp = &sb[(cl * HP + 2 * oy) * WP + 2 * ox];
        float x[3][3];
        #pragma unroll
        for (int dy = 0; dy < 3; ++dy) {
            float2 f = *(const float2*)&sp[dy * WP];
            x[dy][0] = f.x; x[dy][1] = f.y; x[dy][2] = sp[dy * WP + 2];
        }
        const float* wp = w + ((size_t)co_base * CIN + (ci0 + cl)) * 9;
        #pragma unroll
        for (int r = 0; r < CO_R; ++r) {
            const float* wr = wp + (size_t)r * CIN * 9;
            #pragma unroll
            for (int dy = 0; dy < 3; ++dy)
                #pragma unroll
                for (int dx = 0; dx < 3; ++dx)
                    acc[r] = fmaf(wr[dy * 3 + dx], x[dy][dx], acc[r]);
        }
    }
    #pragma unroll
    for (int r = 0; r < CO_R; ++r)
        partial[(((size_t)s * 10 + b) * COUT + co_base + r) * SP + sp_i] = acc[r];
}

template<int COUT,int SP,int S>
__global__ void conv_reduce_relu(const float* __restrict__ partial, const float* __restrict__ bias,
                                 float* __restrict__ out, int total)
{
    int i = blockIdx.x * 256 + threadIdx.x;
    if (i >= total) return;
    int sp = i % SP; int co = (i / SP) % COUT; int b = i / (SP * COUT);
    float acc = bias[co];
    #pragma unroll
    for (int s = 0; s < S; ++s) acc += partial[(((size_t)s * 10 + b) * COUT + co) * SP + sp];
    out[i] = fmaxf(acc, 0.f);
}

// ---------------------------------------------------------------------------
// d0/d1 split-K quad (unchanged)
// ---------------------------------------------------------------------------
template<int CIN,int COUT,int HIN,int CK,int CO_R,int QPW>
__global__ __launch_bounds__(256) void deconv_quad_splitk(const float* __restrict__ in,
    const float* __restrict__ w, float* __restrict__ partial)
{
    constexpr int CPW = 64 / QPW;
    constexpr int HP2 = HIN + 2;
    constexpr int SP = 4 * HIN * HIN;
    constexpr int WOUT = 2 * HIN;
    static_assert(QPW == HIN * HIN, "wave quads cover input plane");
    __shared__ float sb[CK * HP2 * HP2];
    const int b = blockIdx.y, s = blockIdx.z;
    const int lane = threadIdx.x & 63;
    const int wv = threadIdx.x >> 6;
    const int q = lane % QPW;
    const int co_off = lane / QPW;
    const int t = q / HIN, u = q % HIN;
    const int co_base = (blockIdx.x * 4 + wv) * CPW * CO_R + co_off * CO_R;
    const int ci0 = s * CK;
    const float* inb = in + (size_t)b * CIN * HIN * HIN;

    for (int i = threadIdx.x; i < CK * HP2 * HP2; i += 256) {
        int c = i % HP2; int r = (i / HP2) % HP2; int cl = i / (HP2 * HP2);
        int gr = r - 1, gc = c - 1;
        float v = 0.f;
        if (gr >= 0 && gr < HIN && gc >= 0 && gc < HIN)
            v = inb[((size_t)(ci0 + cl) * HIN + gr) * HIN + gc];
        sb[i] = v;
    }
    __syncthreads();

    float acc[CO_R][4] = {};
    #pragma unroll 4
    for (int cl = 0; cl < CK; ++cl) {
        const float* sp = &sb[(cl * HP2 + t) * HP2 + u];
        float x00 = sp[0],       x01 = sp[1],       x02 = sp[2];
        float x10 = sp[HP2],     x11 = sp[HP2+1],   x12 = sp[HP2+2];
        float x20 = sp[2*HP2],   x21 = sp[2*HP2+1], x22 = sp[2*HP2+2];
        const float* wp = w + ((size_t)(ci0 + cl) * COUT + co_base) * 16;
        #pragma unroll
        for (int r = 0; r < CO_R; ++r) {
            const float* W_ = wp + r * 16;
            acc[r][0] += W_[5]*x11 + W_[7]*x10 + W_[13]*x01 + W_[15]*x00;
            acc[r][1] += W_[4]*x12 + W_[6]*x11 + W_[12]*x02 + W_[14]*x01;
            acc[r][2] += W_[1]*x21 + W_[3]*x20 + W_[9]*x11  + W_[11]*x10;
            acc[r][3] += W_[0]*x22 + W_[2]*x21 + W_[8]*x12  + W_[10]*x11;
        }
    }
    #pragma unroll
    for (int r = 0; r < CO_R; ++r) {
        float* pp = partial + (((size_t)s * 10 + b) * COUT + co_base + r) * SP;
        pp[(2*t)   * WOUT + 2*u]     = acc[r][0];
        pp[(2*t)   * WOUT + 2*u + 1] = acc[r][1];
        pp[(2*t+1) * WOUT + 2*u]     = acc[r][2];
        pp[(2*t+1) * WOUT + 2*u + 1] = acc[r][3];
    }
}

// ---------------------------------------------------------------------------
// d2/d3/d4 DIRECT (R8 template, proven): 4 waves/block, thread = one 2x2 quad
// x CO_R cos; 9 global loads per ci (L1/L2-served), wave-uniform scalar
// weights; no LDS, no barriers. co_base = (z*4 + wave)*CO_R.
// ---------------------------------------------------------------------------
template<int CIN,int COUT,int HIN,int CO_R>
__global__ __launch_bounds__(256) void deconv_quad_direct(const float* __restrict__ in,
    const float* __restrict__ w, const float* __restrict__ bias, float* __restrict__ out)
{
    constexpr int WIN = HIN;
    constexpr int HOUT = 2 * HIN, WOUT = 2 * WIN;
    constexpr int TILES_W = HIN / 8;
    static_assert(HIN % 8 == 0, "8x8 quad tiles");

    const int lane = threadIdx.x & 63;
    const int wv   = __builtin_amdgcn_readfirstlane((int)(threadIdx.x >> 6));
    const int tile = blockIdx.x;
    const int tr = tile / TILES_W, tc = tile % TILES_W;
    const int b  = blockIdx.y;
    const int co_base = (blockIdx.z * 4 + wv) * CO_R;

    const int t = tr * 8 + (lane >> 3);
    const int u = tc * 8 + (lane & 7);
    const bool mr0 = t > 0, mr2 = t < HIN - 1, mc0 = u > 0, mc2 = u < WIN - 1;
    const int tm = mr0 ? t - 1 : t, tp = mr2 ? t + 1 : t;
    const int um = mc0 ? u - 1 : u, up = mc2 ? u + 1 : u;
    const int o00 = tm*WIN+um, o01 = tm*WIN+u, o02 = tm*WIN+up;
    const int o10 = t *WIN+um, o11 = t *WIN+u, o12 = t *WIN+up;
    const int o20 = tp*WIN+um, o21 = tp*WIN+u, o22 = tp*WIN+up;

    const float* p = in + (size_t)b * CIN * HIN * WIN;
    float acc[CO_R][4] = {};

    #pragma unroll 2
    for (int ci = 0; ci < CIN; ++ci) {
        float x00 = p[o00], x01 = p[o01], x02 = p[o02];
        float x10 = p[o10], x11 = p[o11], x12 = p[o12];
        float x20 = p[o20], x21 = p[o21], x22 = p[o22];
        x00 = (mr0 && mc0) ? x00 : 0.f;
        x01 = mr0 ? x01 : 0.f;
        x02 = (mr0 && mc2) ? x02 : 0.f;
        x10 = mc0 ? x10 : 0.f;
        x12 = mc2 ? x12 : 0.f;
        x20 = (mr2 && mc0) ? x20 : 0.f;
        x21 = mr2 ? x21 : 0.f;
        x22 = (mr2 && mc2) ? x22 : 0.f;

        const float* wp = w + ((size_t)ci * COUT + co_base) * 16;   // wave-uniform
        #pragma unroll
        for (int r = 0; r < CO_R; ++r) {
            const float* W_ = wp + r * 16;
            acc[r][0] += W_[5]*x11 + W_[7]*x10 + W_[13]*x01 + W_[15]*x00;
            acc[r][1] += W_[4]*x12 + W_[6]*x11 + W_[12]*x02 + W_[14]*x01;
            acc[r][2] += W_[1]*x21 + W_[3]*x20 + W_[9]*x11  + W_[11]*x10;
            acc[r][3] += W_[0]*x22 + W_[2]*x21 + W_[8]*x12  + W_[10]*x11;
        }
        p += HIN * WIN;
    }

    #pragma unroll
    for (int r = 0; r < CO_R; ++r) {
        int co = co_base + r;
        float bi = bias[co];
        float* ob = out + (((size_t)b * COUT + co) * HOUT + 2 * t) * WOUT + 2 * u;
        float2 v0, v1;
        v0.x = fmaxf(acc[r][0] + bi, 0.f);
        v0.y = fmaxf(acc[r][1] + bi, 0.f);
        v1.x = fmaxf(acc[r][2] + bi, 0.f);
        v1.y = fmaxf(acc[r][3] + bi, 0.f);
        *(float2*)ob = v0;
        *(float2*)&ob[WOUT] = v1;
    }
}

// ---------------------------------------------------------------------------
// Split-K FC (unchanged)
// ---------------------------------------------------------------------------
template<int KC>
__global__ __launch_bounds__(256) void fc_splitk(const float* __restrict__ in,
    const float* __restrict__ W, float* __restrict__ partial, int K, int N)
{
    __shared__ float s_in[10 * KC];
    const int o = blockIdx.x * 256 + threadIdx.x;
    const int k0 = blockIdx.y * KC;
    for (int i = threadIdx.x; i < 10 * KC; i += 256) {
        int b = i / KC, k = i % KC;
        s_in[i] = in[(size_t)b * K + k0 + k];
    }
    __syncthreads();

    float acc[10];
    #pragma unroll
    for (int b = 0; b < 10; ++b) acc[b] = 0.f;
    const float* wp = W + (size_t)k0 * N + o;
    #pragma unroll 4
    for (int k = 0; k < KC; ++k) {
        float wv = wp[(size_t)k * N];
        #pragma unroll
        for (int b = 0; b < 10; ++b) acc[b] = fmaf(wv, s_in[b * KC + k], acc[b]);
    }
    float* pp = partial + ((size_t)blockIdx.y * 10) * N + o;
    #pragma unroll
    for (int b = 0; b < 10; ++b) pp[(size_t)b * N] = acc[b];
}

__global__ void fc_reduce_relu(const float* __restrict__ partial, const float* __restrict__ bias,
                               float* __restrict__ out, int N, int S)
{
    int i = blockIdx.x * 256 + threadIdx.x;
    if (i >= 10 * N) return;
    int o = i % N, b = i / N;
    float acc = bias[o];
    for (int s = 0; s < S; ++s) acc += partial[((size_t)s * 10 + b) * N + o];
    out[(size_t)b * N + o] = fmaxf(acc, 0.f);
}

// ---------------------------------------------------------------------------
// Final fused: 1x1 convs + geometry (unchanged)
// ---------------------------------------------------------------------------
__global__ __launch_bounds__(256) void final_fused_v2(const float* __restrict__ h,
    const float* __restrict__ xyzw, const float* __restrict__ xyzb,
    const float* __restrict__ maskw, const float* __restrict__ maskb,
    const float* __restrict__ quat, float* __restrict__ out)
{
    const int V = 8, HW = 128 * 128, C = 48, Bn = 10, VHW = V * HW;
    __shared__ float4 sh[48 * 32];
    int b = blockIdx.y, tile = blockIdx.x;
    const float4* hb = (const float4*)h;
    for (int i = threadIdx.x; i < C * 32; i += 256) {
        int ci = i >> 5, p = i & 31;
        sh[i] = hb[(size_t)(b * C + ci) * (HW / 4) + tile * 32 + p];
    }
    __syncthreads();

    int pl = threadIdx.x & 31, v = threadIdx.x >> 5;
    float4 xr = {0,0,0,0}, yr = {0,0,0,0}, zr = {0,0,0,0}, mm = {0,0,0,0};
    const float* wx = xyzw + (size_t)(v * 3 + 0) * C;
    const float* wy = xyzw + (size_t)(v * 3 + 1) * C;
    const float* wz = xyzw + (size_t)(v * 3 + 2) * C;
    const float* wm = maskw + (size_t)v * C;
    for (int ci = 0; ci < C; ++ci) {
        float4 hv = sh[ci * 32 + pl];
        float a;
        a = wx[ci]; xr.x += a*hv.x; xr.y += a*hv.y; xr.z += a*hv.z; xr.w += a*hv.w;
        a = wy[ci]; yr.x += a*hv.x; yr.y += a*hv.y; yr.z += a*hv.z; yr.w += a*hv.w;
        a = wz[ci]; zr.x += a*hv.x; zr.y += a*hv.y; zr.z += a*hv.z; zr.w += a*hv.w;
        a = wm[ci]; mm.x += a*hv.x; mm.y += a*hv.y; mm.z += a*hv.z; mm.w += a*hv.w;
    }
    float bxv = xyzb[v * 3 + 0], byv = xyzb[v * 3 + 1], bzv = xyzb[v * 3 + 2], bmv = maskb[v];

    float qw = quat[v*4+0], qx = quat[v*4+1], qy = quat[v*4+2], qz = quat[v*4+3];
    float R00 = 1.f - 2.f*(qy*qy + qz*qz), R01 = 2.f*(qx*qy - qw*qz), R02 = 2.f*(qx*qz + qw*qy);
    float R10 = 2.f*(qx*qy + qw*qz), R11 = 1.f - 2.f*(qx*qx + qz*qz), R12 = 2.f*(qy*qz - qw*qx);
    float R20 = 2.f*(qx*qz - qw*qy), R21 = 2.f*(qy*qz + qw*qx), R22 = 1.f - 2.f*(qx*qx + qy*qy);

    float4 o0, o1, o2, om;
    float* X = (float*)&xr; float* Y = (float*)&yr; float* Z = (float*)&zr; float* M = (float*)&mm;
    float* O0 = (float*)&o0; float* O1 = (float*)&o1; float* O2 = (float*)&o2; float* OM = (float*)&om;
    #pragma unroll
    for (int j = 0; j < 4; ++j) {
        float camX = (X[j] + bxv) * (1.f / 64.f) - 0.5f;
        float camY = -(Y[j] + byv) * (1.f / 64.f) + 0.5f;
        float camZ = -((Z[j] + bzv) + 1.0f);
        O0[j] = R00 * camX + R10 * camY + R20 * camZ;
        O1[j] = R01 * camX + R11 * camY + R21 * camZ;
        O2[j] = R02 * camX + R12 * camY + R22 * camZ;
        OM[j] = M[j] + bmv;
    }

    size_t o = (size_t)v * HW + tile * 128 + pl * 4;
    float4* op = (float4*)out;
    op[((size_t)(b * 3 + 0) * VHW + o) >> 2] = o0;
    op[((size_t)(b * 3 + 1) * VHW + o) >> 2] = o1;
    op[((size_t)(b * 3 + 2) * VHW + o) >> 2] = o2;
    op[((size_t)Bn * 3 * VHW + (size_t)b * VHW + o) >> 2] = om;
}

// ---------------------------------------------------------------------------

extern "C" void kernel_launch(void* const* d_in, const int* in_sizes, int n_in,
                              void* d_out, int out_size, void* d_ws, size_t ws_size,
                              hipStream_t stream)
{
    const float* x    = (const float*)d_in[0];
    const float* ew0  = (const float*)d_in[1];
    const float* eb0  = (const float*)d_in[2];
    const float* ew1  = (const float*)d_in[3];
    const float* eb1  = (const float*)d_in[4];
    const float* ew2  = (const float*)d_in[5];
    const float* eb2  = (const float*)d_in[6];
    const float* ew3  = (const float*)d_in[7];
    const float* eb3  = (const float*)d_in[8];
    const float* efw  = (const float*)d_in[9];
    const float* efb  = (const float*)d_in[10];
    const float* dfw  = (const float*)d_in[11];
    const float* dfb  = (const float*)d_in[12];
    const float* dw0  = (const float*)d_in[13];
    const float* db0  = (const float*)d_in[14];
    const float* dw1  = (const float*)d_in[15];
    const float* db1  = (const float*)d_in[16];
    const float* dw2  = (const float*)d_in[17];
    const float* db2  = (const float*)d_in[18];
    const float* dw3  = (const float*)d_in[19];
    const float* db3  = (const float*)d_in[20];
    const float* dw4  = (const float*)d_in[21];
    const float* db4  = (const float*)d_in[22];
    const float* xyzw = (const float*)d_in[23];
    const float* xyzb = (const float*)d_in[24];
    const float* maskw= (const float*)d_in[25];
    const float* maskb= (const float*)d_in[26];
    const float* quat = (const float*)d_in[27];
    float* out = (float*)d_out;

    float* A   = (float*)d_ws;
    float* Bb  = A + 7864320;
    float* P1  = A;                 // fc1 partials 128*10*512 = 655,360
    float* L   = A + 1000000;       // latent 5120
    float* P2  = Bb + 1000000;      // fc2 partials 16*10*4096 = 655,360
    float* H0  = Bb;                // fc2 out 40,960
    float* PC1 = A + 2000000;       // conv1 partials 2,621,440
    float* PC2 = A + 2000000;       // conv2 partials 983,040
    float* PC3 = Bb + 500000;       // conv3 partials 491,520
    float* PD0 = A + 2000000;       // d0 partials 491,520
    float* PD1 = Bb + 1000000;      // d1 partials 1,310,720

    const int TB = 256;

    // encoder
    conv3x3_c3<<<3840, 256, 0, stream>>>(x, ew0, eb0, A);
    conv_splitk_big<96,128,32,32,8,6,16><<<dim3(8,10,8), 256, 0, stream>>>(A, ew1, PC1);
    conv_reduce_relu<128,256,8><<<CDIV(327680,TB), TB, 0, stream>>>(PC1, eb1, Bb, 327680);
    conv_small_splitk<128,192,16,16,16,3,4><<<dim3(16,10,8), 256, 0, stream>>>(Bb, ew2, PC2);
    conv_reduce_relu<192,64,8><<<CDIV(122880,TB), TB, 0, stream>>>(PC2, eb2, A, 122880);
    conv_small_splitk<192,256,8,8,16,1,16><<<dim3(16,10,12), 256, 0, stream>>>(A, ew3, PC3);
    conv_reduce_relu<256,16,12><<<CDIV(40960,TB), TB, 0, stream>>>(PC3, eb3, Bb, 40960);

    // fc
    fc_splitk<32><<<dim3(2, 128), 256, 0, stream>>>(Bb, efw, P1, 4096, 512);
    fc_reduce_relu<<<CDIV(10 * 512, TB), TB, 0, stream>>>(P1, efb, L, 512, 128);
    fc_splitk<32><<<dim3(16, 16), 256, 0, stream>>>(L, dfw, P2, 512, 4096);
    fc_reduce_relu<<<CDIV(10 * 4096, TB), TB, 0, stream>>>(P2, dfb, H0, 4096, 16);

    // decoder
    deconv_quad_splitk<256,192,4,64,1,16><<<dim3(12,10,4), 256, 0, stream>>>(H0, dw0, PD0);
    conv_reduce_relu<192,64,4><<<CDIV(122880,TB), TB, 0, stream>>>(PD0, db0, A, 122880);
    deconv_quad_splitk<192,128,8,48,2,64><<<dim3(16,10,4), 256, 0, stream>>>(A, dw1, PD1);
    conv_reduce_relu<128,256,4><<<CDIV(327680,TB), TB, 0, stream>>>(PD1, db1, Bb, 327680);

    // d2: direct (input 131 KB/b -> z-redundancy is L2-free), 480 blocks
    deconv_quad_direct<128, 96, 16, 2><<<dim3( 4, 10, 12), 256, 0, stream>>>(Bb, dw2, db2, A);
    // d3: R8 proven config, 1280 blocks
    deconv_quad_direct< 96, 64, 32, 2><<<dim3(16, 10,  8), 256, 0, stream>>>(A,  dw3, db3, Bb);
    // d4: all 48 cos in ONE 4-wave block (CO_R=12, z=1) -> input read once, 640 blocks
    deconv_quad_direct< 64, 48, 64,12><<<dim3(64, 10,  1), 256, 0, stream>>>(Bb, dw4, db4, A);

    // fused 1x1 convs + geometry -> d_out
    final_fused_v2<<<dim3(128, 10), 256, 0, stream>>>(A, xyzw, xyzb, maskw, maskb, quat, out);
}